// Round 3
// baseline (43.900 us; speedup 1.0000x reference)
//
#include <hip/hip_runtime.h>
#include <math.h>
#include <stdint.h>

#define NHEAD 4
#define DD 100
#define NW 39            // word rows
#define BLOCK 256
#define NS 4             // sites per block
#define ALPHA 0.3f

typedef __attribute__((address_space(3))) uint32_t lds_t;
typedef const __attribute__((address_space(1))) uint32_t glb_t;

// Stage one 4000-float site tile into LDS (linear, 16 B/lane async DMA).
// Per wave: exactly 4 global_load_lds issues (vmcnt bookkeeping relies on this).
__device__ __forceinline__ void stage_tile(const float* xs, float* buf, int tid, int wv) {
#pragma unroll
    for (int i = 0; i < 4; ++i) {
        const int cf = i * BLOCK + tid;          // float4 chunk 0..1023
        if (cf < 1000) {
            glb_t* g = (glb_t*)(xs + cf * 4);
            lds_t* l = (lds_t*)(buf + (i * BLOCK + wv * 64) * 4); // wave-uniform base
            __builtin_amdgcn_global_load_lds(g, l, 16, 0, 0);
        }
    }
}

__global__ __launch_bounds__(BLOCK, 4) void ts_enc(
    const float* __restrict__ x,       // [4800][40][100]
    const float* __restrict__ w_att,   // [4][100]
    const float* __restrict__ b_att,   // [4][100]
    float* __restrict__ out)           // [4800][400]
{
    __shared__ float tile[2][40 * DD];   // double-buffered site tiles (32 KB)
    __shared__ float scp[NHEAD][4][40];  // [head][wave-partial][n] (bank-clean)

    const int tid  = threadIdx.x;
    const int wv   = __builtin_amdgcn_readfirstlane(tid >> 6);
    const int lane = tid & 63;
    const int site0 = blockIdx.x * NS;

    // prologue: stage site 0
    stage_tile(x + (size_t)site0 * (40 * DD), tile[0], tid, wv);

#pragma unroll
    for (int s = 0; s < NS; ++s) {
        const int site = site0 + s;
        const float* tile_s = tile[s & 1];

        // ---- tile s ready: counted wait (never drain the pipeline store) ----
        if (s == 0) { asm volatile("s_waitcnt vmcnt(0)" ::: "memory"); }
        else        { asm volatile("s_waitcnt vmcnt(1)" ::: "memory"); } // 1 = prev site's store
        __builtin_amdgcn_s_barrier();
        __builtin_amdgcn_sched_barrier(0);

        // ---- issue next site's staging EARLY: hides HBM latency under compute ----
        if (s + 1 < NS)
            stage_tile(x + (size_t)(site + 1) * (40 * DD), tile[(s + 1) & 1], tid, wv);
        __builtin_amdgcn_sched_barrier(0);

        // ---- Phase A: scores, d-chunks split across waves, lane = n, all 4 heads ----
        const bool act = lane < NW;
        const float* wrow = tile_s + (1 + lane) * DD;
        float acc[NHEAD] = {0.f, 0.f, 0.f, 0.f};
        for (int c = wv; c < 25; c += 4) {
            const float4 te4 = *(const float4*)(tile_s + c * 4);      // broadcast LDS read
            float4 v4 = make_float4(0.f, 0.f, 0.f, 0.f);
            if (act) v4 = *(const float4*)(wrow + c * 4);
            #pragma unroll
            for (int h = 0; h < NHEAD; ++h) {
                const float4 w4 = *(const float4*)(w_att + h * DD + c * 4); // scalar-cache
                const float4 b4 = *(const float4*)(b_att + h * DD + c * 4);
                float p0 = fmaf(v4.x, w4.x, b4.x);
                float p1 = fmaf(v4.y, w4.y, b4.y);
                float p2 = fmaf(v4.z, w4.z, b4.z);
                float p3 = fmaf(v4.w, w4.w, b4.w);
                p0 = fmaxf(p0, 0.f) + ALPHA * fminf(p0, 0.f);   // leaky, exact
                p1 = fmaxf(p1, 0.f) + ALPHA * fminf(p1, 0.f);
                p2 = fmaxf(p2, 0.f) + ALPHA * fminf(p2, 0.f);
                p3 = fmaxf(p3, 0.f) + ALPHA * fminf(p3, 0.f);
                acc[h] += fmaf(te4.x, p0, fmaf(te4.y, p1, fmaf(te4.z, p2, te4.w * p3)));
            }
        }
        if (act) {
            scp[0][wv][lane] = acc[0];
            scp[1][wv][lane] = acc[1];
            scp[2][wv][lane] = acc[2];
            scp[3][wv][lane] = acc[3];
        }
        asm volatile("s_waitcnt lgkmcnt(0)" ::: "memory");
        __builtin_amdgcn_s_barrier();
        __builtin_amdgcn_sched_barrier(0);

        // ---- Phase B: softmax in-wave (wave wv owns head wv, lane = n) ----
        float sc = -INFINITY;
        if (act) sc = (scp[wv][0][lane] + scp[wv][1][lane])
                    + (scp[wv][2][lane] + scp[wv][3][lane]);
        float mx = sc;
        #pragma unroll
        for (int off = 32; off; off >>= 1) mx = fmaxf(mx, __shfl_xor(mx, off));
        float p = act ? __expf(sc - mx) : 0.f;
        float sm = p;
        #pragma unroll
        for (int off = 32; off; off >>= 1) sm += __shfl_xor(sm, off);
        const float a = p / sm;        // lane n holds att[head=wv][n]; 0 for n>=39

        // ---- Phase C: out[wv][d] = sum_n att[n]*words[n][d]; att via shuffle, no barrier ----
        const int half = lane >> 5;
        const int dc   = lane & 31;
        const int dcc  = dc < 25 ? dc : 24;          // clamp: keep idle lanes in-bounds
        float4 ca = make_float4(0.f, 0.f, 0.f, 0.f);
        const float* wb = tile_s + DD + dcc * 4;
        #pragma unroll
        for (int i = 0; i < 20; ++i) {
            const int n  = half * 20 + i;            // half1,i=19 -> n=39: att=0
            const int nn = n < NW ? n : NW - 1;      // clamp read in-bounds
            const float attn = __shfl(a, n);
            const float4 wd = *(const float4*)(wb + nn * DD);
            ca.x = fmaf(attn, wd.x, ca.x);
            ca.y = fmaf(attn, wd.y, ca.y);
            ca.z = fmaf(attn, wd.z, ca.z);
            ca.w = fmaf(attn, wd.w, ca.w);
        }
        ca.x += __shfl_xor(ca.x, 32);
        ca.y += __shfl_xor(ca.y, 32);
        ca.z += __shfl_xor(ca.z, 32);
        ca.w += __shfl_xor(ca.w, 32);
        if (half == 0 && dc < 25)                    // 1 store instr per wave per site
            *(float4*)(out + (size_t)site * (NHEAD * DD) + wv * DD + dc * 4) = ca;
    }
}

extern "C" void kernel_launch(void* const* d_in, const int* in_sizes, int n_in,
                              void* d_out, int out_size, void* d_ws, size_t ws_size,
                              hipStream_t stream) {
    const float* x     = (const float*)d_in[0];
    const float* w_att = (const float*)d_in[1];
    const float* b_att = (const float*)d_in[2];
    float* out = (float*)d_out;

    const int sites = 8 * 30 * 20;            // 4800
    ts_enc<<<sites / NS, BLOCK, 0, stream>>>(x, w_att, b_att, out);
}

// Round 4
// 28.409 us; speedup vs baseline: 1.5453x; 1.5453x over previous
//
#include <hip/hip_runtime.h>
#include <math.h>
#include <stdint.h>

#define NHEAD 4
#define DD 100
#define NW 39            // word rows
#define BLOCK 256

typedef __attribute__((address_space(3))) uint32_t lds_t;
typedef const __attribute__((address_space(1))) uint32_t glb_t;

__global__ __launch_bounds__(BLOCK, 8) void ts_enc(
    const float* __restrict__ x,       // [4800][40][100]
    const float* __restrict__ w_att,   // [4][100]
    const float* __restrict__ b_att,   // [4][100]
    float* __restrict__ out)           // [4800][400]
{
    __shared__ float tile[40 * DD];      // 16 KB: row0 = type_emb, rows 1..39 = words
    __shared__ float scp[4][NHEAD][40];  // [wave-partial][head][n]

    const int tid  = threadIdx.x;
    const int wv   = __builtin_amdgcn_readfirstlane(tid >> 6);
    const int lane = tid & 63;
    const float* xsite = x + (size_t)blockIdx.x * (40 * DD);

    // ---- stage site tile: async global->LDS, 16 B/lane, 1000 float4 chunks ----
    #pragma unroll
    for (int i = 0; i < 4; ++i) {
        const int cf = i * BLOCK + tid;
        if (cf < 1000) {
            glb_t* g = (glb_t*)(xsite + cf * 4);
            lds_t* l = (lds_t*)(tile + (i * BLOCK + wv * 64) * 4);
            __builtin_amdgcn_global_load_lds(g, l, 16, 0, 0);
        }
    }
    __syncthreads();

    // ---- Phase A: scores; d-chunks split across waves, lane = n, all 4 heads ----
    // te*leaky(p) == (0.65*te)*p + (0.35*te)*|p|  (|p| = free input modifier)
    const bool act  = lane < NW;
    const int  nrow = act ? lane : NW - 1;            // clamp idle lanes in-bounds
    const float* wrow = tile + (1 + nrow) * DD;
    float acc[NHEAD] = {0.f, 0.f, 0.f, 0.f};

    for (int c = wv; c < 25; c += 4) {
        const float4 te4 = *(const float4*)(tile + c * 4);   // broadcast
        const float4 v4  = *(const float4*)(wrow + c * 4);
        const float a65x = 0.65f * te4.x, a35x = 0.35f * te4.x;
        const float a65y = 0.65f * te4.y, a35y = 0.35f * te4.y;
        const float a65z = 0.65f * te4.z, a35z = 0.35f * te4.z;
        const float a65w = 0.65f * te4.w, a35w = 0.35f * te4.w;
        #pragma unroll
        for (int h = 0; h < NHEAD; ++h) {
            const float4 w4 = *(const float4*)(w_att + h * DD + c * 4); // scalar-cache
            const float4 b4 = *(const float4*)(b_att + h * DD + c * 4);
            float p0 = fmaf(v4.x, w4.x, b4.x);
            float p1 = fmaf(v4.y, w4.y, b4.y);
            float p2 = fmaf(v4.z, w4.z, b4.z);
            float p3 = fmaf(v4.w, w4.w, b4.w);
            float t  = fmaf(a65x, p0, fmaf(a35x, fabsf(p0), acc[h]));
            t        = fmaf(a65y, p1, fmaf(a35y, fabsf(p1), t));
            t        = fmaf(a65z, p2, fmaf(a35z, fabsf(p2), t));
            acc[h]   = fmaf(a65w, p3, fmaf(a35w, fabsf(p3), t));
        }
    }
    if (act) {
        scp[wv][0][lane] = acc[0];
        scp[wv][1][lane] = acc[1];
        scp[wv][2][lane] = acc[2];
        scp[wv][3][lane] = acc[3];
    }
    __syncthreads();

    // ---- Phase B: softmax in-wave (wave wv = head wv, lane = n) ----
    float sc = -INFINITY;
    if (act) sc = (scp[0][wv][lane] + scp[1][wv][lane])
                + (scp[2][wv][lane] + scp[3][wv][lane]);
    float mx = sc;
    #pragma unroll
    for (int off = 32; off; off >>= 1) mx = fmaxf(mx, __shfl_xor(mx, off));
    float p = act ? __expf(sc - mx) : 0.f;
    float sm = p;
    #pragma unroll
    for (int off = 32; off; off >>= 1) sm += __shfl_xor(sm, off);
    const float a = p / sm;    // lane n holds att[head=wv][n]; 0 for n>=39

    // ---- Phase C: out[wv][d] = sum_n att[n]*words[n][d]; att via shuffle ----
    const int half = lane >> 5;
    const int dc   = lane & 31;
    const int dcc  = dc < 25 ? dc : 24;               // clamp idle lanes
    float4 ca = make_float4(0.f, 0.f, 0.f, 0.f);
    const float* wb = tile + DD + dcc * 4;
    #pragma unroll
    for (int i = 0; i < 20; ++i) {
        const int n  = half * 20 + i;                 // half1,i=19 -> n=39: att=0
        const int nn = n < NW ? n : NW - 1;
        const float attn = __shfl(a, n);
        const float4 wd = *(const float4*)(wb + nn * DD);
        ca.x = fmaf(attn, wd.x, ca.x);
        ca.y = fmaf(attn, wd.y, ca.y);
        ca.z = fmaf(attn, wd.z, ca.z);
        ca.w = fmaf(attn, wd.w, ca.w);
    }
    ca.x += __shfl_xor(ca.x, 32);
    ca.y += __shfl_xor(ca.y, 32);
    ca.z += __shfl_xor(ca.z, 32);
    ca.w += __shfl_xor(ca.w, 32);
    if (half == 0 && dc < 25)
        *(float4*)(out + (size_t)blockIdx.x * (NHEAD * DD) + wv * DD + dc * 4) = ca;
}

extern "C" void kernel_launch(void* const* d_in, const int* in_sizes, int n_in,
                              void* d_out, int out_size, void* d_ws, size_t ws_size,
                              hipStream_t stream) {
    const float* x     = (const float*)d_in[0];
    const float* w_att = (const float*)d_in[1];
    const float* b_att = (const float*)d_in[2];
    float* out = (float*)d_out;

    const int sites = 8 * 30 * 20;   // 4800
    ts_enc<<<sites, BLOCK, 0, stream>>>(x, w_att, b_att, out);
}

// Round 5
// 27.659 us; speedup vs baseline: 1.5872x; 1.0271x over previous
//
#include <hip/hip_runtime.h>
#include <math.h>
#include <stdint.h>

#define NHEAD 4
#define DD 100
#define NW 39            // word rows
#define BLOCK 256

typedef __attribute__((address_space(3))) uint32_t lds_t;
typedef const __attribute__((address_space(1))) uint32_t glb_t;

__global__ __launch_bounds__(BLOCK, 8) void ts_enc(
    const float* __restrict__ x,       // [4800][40][100]
    const float* __restrict__ w_att,   // [4][100]
    const float* __restrict__ b_att,   // [4][100]
    float* __restrict__ out)           // [4800][400]
{
    __shared__ float tile[40 * DD];      // 16 KB: row0 = type_emb, rows 1..39 = words
    __shared__ float scp[4][NHEAD][40];  // [wave-partial][head][n]
    __shared__ float att_T[40][NHEAD];   // [n][head]

    const int tid  = threadIdx.x;
    const int wv   = __builtin_amdgcn_readfirstlane(tid >> 6);
    const int lane = tid & 63;
    const float* xsite = x + (size_t)blockIdx.x * (40 * DD);

    // ---- stage site tile: async global->LDS, 16 B/lane, 1000 float4 chunks ----
    #pragma unroll
    for (int i = 0; i < 4; ++i) {
        const int cf = i * BLOCK + tid;
        if (cf < 1000) {
            glb_t* g = (glb_t*)(xsite + cf * 4);
            lds_t* l = (lds_t*)(tile + (i * BLOCK + wv * 64) * 4);
            __builtin_amdgcn_global_load_lds(g, l, 16, 0, 0);
        }
    }
    __syncthreads();

    // ---- Phase A: scores; d-chunks split across waves, lane = n, all 4 heads ----
    // te*leaky(p) == (0.65*te)*p + (0.35*te)*|p|  (|p| = free input modifier)
    const bool act  = lane < NW;
    const int  nrow = act ? lane : NW - 1;            // clamp idle lanes in-bounds
    const float* wrow = tile + (1 + nrow) * DD;
    float acc[NHEAD] = {0.f, 0.f, 0.f, 0.f};

    for (int c = wv; c < 25; c += 4) {
        const float4 te4 = *(const float4*)(tile + c * 4);   // broadcast (1 addr)
        const float4 v4  = *(const float4*)(wrow + c * 4);   // 5-way = at bank floor
        const float a65x = 0.65f * te4.x, a35x = 0.35f * te4.x;
        const float a65y = 0.65f * te4.y, a35y = 0.35f * te4.y;
        const float a65z = 0.65f * te4.z, a35z = 0.35f * te4.z;
        const float a65w = 0.65f * te4.w, a35w = 0.35f * te4.w;
        #pragma unroll
        for (int h = 0; h < NHEAD; ++h) {
            const float4 w4 = *(const float4*)(w_att + h * DD + c * 4); // s_load (uniform)
            const float4 b4 = *(const float4*)(b_att + h * DD + c * 4);
            float p0 = fmaf(v4.x, w4.x, b4.x);
            float p1 = fmaf(v4.y, w4.y, b4.y);
            float p2 = fmaf(v4.z, w4.z, b4.z);
            float p3 = fmaf(v4.w, w4.w, b4.w);
            float t  = fmaf(a65x, p0, fmaf(a35x, fabsf(p0), acc[h]));
            t        = fmaf(a65y, p1, fmaf(a35y, fabsf(p1), t));
            t        = fmaf(a65z, p2, fmaf(a35z, fabsf(p2), t));
            acc[h]   = fmaf(a65w, p3, fmaf(a35w, fabsf(p3), t));
        }
    }
    if (act) {
        scp[wv][0][lane] = acc[0];
        scp[wv][1][lane] = acc[1];
        scp[wv][2][lane] = acc[2];
        scp[wv][3][lane] = acc[3];
    }
    __syncthreads();

    // ---- Phase B: softmax in-wave (wave wv = head wv, lane = n) ----
    float sc = -INFINITY;
    if (act) sc = (scp[0][wv][lane] + scp[1][wv][lane])
                + (scp[2][wv][lane] + scp[3][wv][lane]);
    float mx = sc;
    #pragma unroll
    for (int off = 32; off; off >>= 1) mx = fmaxf(mx, __shfl_xor(mx, off));
    float p = act ? __expf(sc - mx) : 0.f;
    float sm = p;
    #pragma unroll
    for (int off = 32; off; off >>= 1) sm += __shfl_xor(sm, off);
    if (act) att_T[lane][wv] = p / sm;   // one b32 write per wave
    __syncthreads();                     // last barrier: tile + att_T stable

    // ---- Phase C: waves 0,1 only; lane = (h, dc); words read broadcast across h ----
    // wave0: dc 0..15, wave1: dc 16..24. Same-address across the 4 h-groups -> free.
    if (wv < 2) {
        const int h  = lane >> 4;
        const int dc = (wv << 4) + (lane & 15);
        if (dc < 25) {
            float4 ca = make_float4(0.f, 0.f, 0.f, 0.f);
            const float* wb = tile + DD + dc * 4;
            #pragma unroll
            for (int n = 0; n < NW; ++n) {
                const float attn = att_T[n][h];              // 4-addr broadcast read
                const float4 wd = *(const float4*)(wb + n * DD); // 16-addr, 2-way banks
                ca.x = fmaf(attn, wd.x, ca.x);
                ca.y = fmaf(attn, wd.y, ca.y);
                ca.z = fmaf(attn, wd.z, ca.z);
                ca.w = fmaf(attn, wd.w, ca.w);
            }
            *(float4*)(out + (size_t)blockIdx.x * (NHEAD * DD) + h * DD + dc * 4) = ca;
        }
    }
}

extern "C" void kernel_launch(void* const* d_in, const int* in_sizes, int n_in,
                              void* d_out, int out_size, void* d_ws, size_t ws_size,
                              hipStream_t stream) {
    const float* x     = (const float*)d_in[0];
    const float* w_att = (const float*)d_in[1];
    const float* b_att = (const float*)d_in[2];
    float* out = (float*)d_out;

    const int sites = 8 * 30 * 20;   // 4800
    ts_enc<<<sites, BLOCK, 0, stream>>>(x, w_att, b_att, out);
}